// Round 5
// baseline (4798.506 us; speedup 1.0000x reference)
//
#include <hip/hip_runtime.h>
#include <hip/hip_bf16.h>
#include <math.h>

// Problem constants (MambaStack reference)
#define DEPTH   2
#define DM      768      // d_model
#define DS      64       // d_state
#define DC      4        // d_conv
#define DI      1536     // d_inner
#define DTR     48       // dt_rank
#define BATCH   4
#define SEQ     2048
#define MROWS   (BATCH*SEQ)          // 8192
#define XDC     (DTR + 2*DS)         // 176 (xdbl cols)
#define NC      8                    // scan chunks
#define TCH     (SEQ/NC)             // 256 timesteps per chunk
#define LOG2E   1.44269504088896f

__device__ __forceinline__ float silu_fast(float x) {
    return x / (1.f + __expf(-x));
}
__device__ __forceinline__ float softplus_acc(float x) {
    return x > 20.f ? x : log1pf(expf(x));
}

// C[M,N] = A[M,K] (row-major, ldA) @ W[N,K]^T  (W row-major, ld = K)
// EPI: 0 = none, 1 = softplus(x + bias[col])
template<int EPI>
__global__ __launch_bounds__(256, 2) void gemm_nt(
    const float* __restrict__ A, int ldA,
    const float* __restrict__ W,
    const float* __restrict__ bias,
    float* __restrict__ C, int ldC,
    int N, int K)
{
    __shared__ float As[8][132];
    __shared__ float Bs[8][132];
    const int tid = threadIdx.x;
    const int bm0 = blockIdx.y * 128;
    const int bn0 = blockIdx.x * 128;
    const int tx = tid & 15;
    const int ty = tid >> 4;
    const int lrow = tid >> 1;
    const int lk4  = (tid & 1) * 4;

    float acc[8][8];
#pragma unroll
    for (int i = 0; i < 8; i++)
#pragma unroll
        for (int j = 0; j < 8; j++) acc[i][j] = 0.f;

    for (int k0 = 0; k0 < K; k0 += 8) {
        const float4 av = *(const float4*)(A + (size_t)(bm0 + lrow) * ldA + (k0 + lk4));
        float4 wv;
        const int wrow = bn0 + lrow;
        if (wrow < N) wv = *(const float4*)(W + (size_t)wrow * K + (k0 + lk4));
        else          wv = make_float4(0.f, 0.f, 0.f, 0.f);
        __syncthreads();
        As[lk4 + 0][lrow] = av.x; As[lk4 + 1][lrow] = av.y;
        As[lk4 + 2][lrow] = av.z; As[lk4 + 3][lrow] = av.w;
        Bs[lk4 + 0][lrow] = wv.x; Bs[lk4 + 1][lrow] = wv.y;
        Bs[lk4 + 2][lrow] = wv.z; Bs[lk4 + 3][lrow] = wv.w;
        __syncthreads();
#pragma unroll
        for (int kk = 0; kk < 8; kk++) {
            const float4 a0 = *(const float4*)&As[kk][ty * 8];
            const float4 a1 = *(const float4*)&As[kk][ty * 8 + 4];
            const float4 b0 = *(const float4*)&Bs[kk][tx * 8];
            const float4 b1 = *(const float4*)&Bs[kk][tx * 8 + 4];
            const float ar[8] = {a0.x, a0.y, a0.z, a0.w, a1.x, a1.y, a1.z, a1.w};
            const float br[8] = {b0.x, b0.y, b0.z, b0.w, b1.x, b1.y, b1.z, b1.w};
#pragma unroll
            for (int i = 0; i < 8; i++)
#pragma unroll
                for (int j = 0; j < 8; j++)
                    acc[i][j] = fmaf(ar[i], br[j], acc[i][j]);
        }
    }

#pragma unroll
    for (int i = 0; i < 8; i++) {
        const int row = bm0 + ty * 8 + i;
#pragma unroll
        for (int j4 = 0; j4 < 8; j4 += 4) {
            const int col = bn0 + tx * 8 + j4;
            if (col + 3 < N) {
                float4 v = make_float4(acc[i][j4], acc[i][j4 + 1], acc[i][j4 + 2], acc[i][j4 + 3]);
                if (EPI == 1) {
                    v.x = softplus_acc(v.x + bias[col + 0]);
                    v.y = softplus_acc(v.y + bias[col + 1]);
                    v.z = softplus_acc(v.z + bias[col + 2]);
                    v.w = softplus_acc(v.w + bias[col + 3]);
                }
                *(float4*)(C + (size_t)row * ldC + col) = v;
            }
        }
    }
}

// C[M,N] = A @ W^T where A is given K-MAJOR per batch: AT[(b*K + k)*SEQ + t].
__global__ __launch_bounds__(256, 2) void gemm_tn(
    const float* __restrict__ AT,
    const float* __restrict__ W,
    float* __restrict__ C, int ldC,
    int N, int K)
{
    __shared__ float As[8][132];
    __shared__ float Bs[8][132];
    const int tid = threadIdx.x;
    const int bm0 = blockIdx.y * 128;
    const int bn0 = blockIdx.x * 128;
    const int bb  = bm0 / SEQ;
    const int t0  = bm0 - bb * SEQ;
    const int tx = tid & 15;
    const int ty = tid >> 4;
    const int arow = tid >> 5;          // k row 0..7
    const int am4  = (tid & 31) * 4;    // m offset 0..124
    const int lrow = tid >> 1;
    const int lk4  = (tid & 1) * 4;

    float acc[8][8];
#pragma unroll
    for (int i = 0; i < 8; i++)
#pragma unroll
        for (int j = 0; j < 8; j++) acc[i][j] = 0.f;

    for (int k0 = 0; k0 < K; k0 += 8) {
        const float4 av = *(const float4*)(AT + ((size_t)(bb * K + k0 + arow)) * SEQ + t0 + am4);
        float4 wv;
        const int wrow = bn0 + lrow;
        if (wrow < N) wv = *(const float4*)(W + (size_t)wrow * K + (k0 + lk4));
        else          wv = make_float4(0.f, 0.f, 0.f, 0.f);
        __syncthreads();
        *(float4*)&As[arow][am4] = av;
        Bs[lk4 + 0][lrow] = wv.x; Bs[lk4 + 1][lrow] = wv.y;
        Bs[lk4 + 2][lrow] = wv.z; Bs[lk4 + 3][lrow] = wv.w;
        __syncthreads();
#pragma unroll
        for (int kk = 0; kk < 8; kk++) {
            const float4 a0 = *(const float4*)&As[kk][ty * 8];
            const float4 a1 = *(const float4*)&As[kk][ty * 8 + 4];
            const float4 b0 = *(const float4*)&Bs[kk][tx * 8];
            const float4 b1 = *(const float4*)&Bs[kk][tx * 8 + 4];
            const float ar[8] = {a0.x, a0.y, a0.z, a0.w, a1.x, a1.y, a1.z, a1.w};
            const float br[8] = {b0.x, b0.y, b0.z, b0.w, b1.x, b1.y, b1.z, b1.w};
#pragma unroll
            for (int i = 0; i < 8; i++)
#pragma unroll
                for (int j = 0; j < 8; j++)
                    acc[i][j] = fmaf(ar[i], br[j], acc[i][j]);
        }
    }

#pragma unroll
    for (int i = 0; i < 8; i++) {
        const int row = bm0 + ty * 8 + i;
#pragma unroll
        for (int j4 = 0; j4 < 8; j4 += 4) {
            const int col = bn0 + tx * 8 + j4;
            if (col + 3 < N) {
                *(float4*)(C + (size_t)row * ldC + col) =
                    make_float4(acc[i][j4], acc[i][j4 + 1], acc[i][j4 + 2], acc[i][j4 + 3]);
            }
        }
    }
}

// Depthwise causal conv (K=4) + SiLU -> uT [b][d][t] only.
__global__ __launch_bounds__(256) void conv_silu_T(
    const float* __restrict__ xz, const float* __restrict__ cw,
    const float* __restrict__ cb, float* __restrict__ uT)
{
    __shared__ float tin[67][65];   // [t(-3..63)][d], +1 pad
    __shared__ float ttr[64][65];   // [d][t], +1 pad
    const int tid = threadIdx.x;
    const int d0 = blockIdx.x * 64, t0 = blockIdx.y * 64, b = blockIdx.z;
    const int cl = tid & 63, q = tid >> 6;

    for (int r = q; r < 67; r += 4) {
        const int t = t0 - 3 + r;
        float v = 0.f;
        if (t >= 0) v = xz[((size_t)b * SEQ + t) * (2 * DI) + d0 + cl];
        tin[r][cl] = v;
    }
    __syncthreads();

    const float4 w = ((const float4*)cw)[d0 + cl];
    const float bb = cb[d0 + cl];
#pragma unroll
    for (int i = 0; i < 16; i++) {
        const int t = q * 16 + i;
        float a = bb;
        a = fmaf(tin[t + 0][cl], w.x, a);
        a = fmaf(tin[t + 1][cl], w.y, a);
        a = fmaf(tin[t + 2][cl], w.z, a);
        a = fmaf(tin[t + 3][cl], w.w, a);
        ttr[cl][t] = silu_fast(a);
    }
    __syncthreads();
#pragma unroll
    for (int i = 0; i < 16; i++) {
        const int d = q * 16 + i;
        uT[((size_t)b * DI + d0 + d) * SEQ + t0 + cl] = ttr[d][cl];  // coalesced in t
    }
}

// Tiled transpose: in[row=b*SEQ+t, coloff+c] (ld ldin) -> out[(b*ncols+c)*SEQ + t]
__global__ __launch_bounds__(256) void trans_r2t(
    const float* __restrict__ in, int ldin, int coloff,
    float* __restrict__ out, int ncols)
{
    __shared__ float tile[64][65];
    const int tid = threadIdx.x;
    const int c0 = blockIdx.x * 64, t0 = blockIdx.y * 64, b = blockIdx.z;
    const int cl = tid & 63, q = tid >> 6;
#pragma unroll
    for (int i = 0; i < 16; i++) {
        const int r = q * 16 + i;
        tile[r][cl] = in[((size_t)b * SEQ + t0 + r) * ldin + coloff + c0 + cl];
    }
    __syncthreads();
#pragma unroll
    for (int i = 0; i < 16; i++) {
        const int cc = q * 16 + i;
        out[((size_t)b * ncols + c0 + cc) * SEQ + t0 + cl] = tile[cl][cc];
    }
}

// ---------------- Chunked selective scan ----------------
// dtT/uT are [b][d][t]: wave-uniform float4 loads (scalar path).
// B/C (lane = state n) are per-lane streams -> software-pipelined prefetch.

// Phase 1: per (b,d,chunk) wave; computes chunk-local h_end and decay product.
__global__ __launch_bounds__(256, 4) void scan_phase1(
    const float* __restrict__ dtT, const float* __restrict__ uT,
    const float* __restrict__ bcT, const float* __restrict__ A_log,
    float* __restrict__ hend, float* __restrict__ prodA)
{
    const int wid  = __builtin_amdgcn_readfirstlane(
                        (int)((blockIdx.x * 256 + threadIdx.x) >> 6));
    const int lane = threadIdx.x & 63;
    const int c  = wid & (NC - 1);
    const int bd = wid >> 3;
    const int b  = bd / DI;
    const int d  = bd - b * DI;

    const float An = -expf(A_log[d * DS + lane]) * LOG2E;
    const float* dtp = dtT + (size_t)bd * SEQ + c * TCH;   // wave-uniform
    const float* up  = uT  + (size_t)bd * SEQ + c * TCH;   // wave-uniform
    const float* Bp  = bcT + ((size_t)b * 128 + lane) * SEQ + c * TCH;

    float4 Bc[4], Bn[4];
#pragma unroll
    for (int g = 0; g < 4; g++) Bc[g] = *(const float4*)(Bp + 4 * g);

    float h = 0.f, sdt = 0.f;
    for (int tb = 0; tb < TCH; tb += 16) {
        if (tb + 16 < TCH) {
#pragma unroll
            for (int g = 0; g < 4; g++)
                Bn[g] = *(const float4*)(Bp + tb + 16 + 4 * g);
        }
#pragma unroll
        for (int g = 0; g < 4; g++) {
            const float4 dt4 = *(const float4*)(dtp + tb + 4 * g);
            const float4 u4  = *(const float4*)(up  + tb + 4 * g);
            h = fmaf(exp2f(dt4.x * An), h, (dt4.x * u4.x) * Bc[g].x); sdt += dt4.x;
            h = fmaf(exp2f(dt4.y * An), h, (dt4.y * u4.y) * Bc[g].y); sdt += dt4.y;
            h = fmaf(exp2f(dt4.z * An), h, (dt4.z * u4.z) * Bc[g].z); sdt += dt4.z;
            h = fmaf(exp2f(dt4.w * An), h, (dt4.w * u4.w) * Bc[g].w); sdt += dt4.w;
        }
#pragma unroll
        for (int g = 0; g < 4; g++) Bc[g] = Bn[g];
    }
    hend [(size_t)wid * DS + lane] = h;
    prodA[(size_t)wid * DS + lane] = exp2f(An * sdt);
}

// Phase 2: per (b,d) wave, serial over chunks; writes h_in into prodA in place.
__global__ __launch_bounds__(256) void scan_phase2(
    float* __restrict__ hend, float* __restrict__ prodA)
{
    const int bd   = (blockIdx.x * 256 + threadIdx.x) >> 6;
    const int lane = threadIdx.x & 63;
    float h = 0.f;
#pragma unroll
    for (int c = 0; c < NC; c++) {
        const size_t off = ((size_t)bd * NC + c) * DS + lane;
        const float pA = prodA[off];
        const float he = hend[off];
        prodA[off] = h;
        h = fmaf(pA, h, he);
    }
}

// Phase 3: resumed scan; writes raw reduced s IN PLACE over dtT (each wave
// reads dt[t] strictly before writing s[t]; per-wave spans are disjoint).
// No gating, no strided access here — that moved to gate_t2r.
__global__ __launch_bounds__(256, 4) void scan_phase3(
    float* dtsT,                                   // in: dtT, out: sT (aliased!)
    const float* __restrict__ uT, const float* __restrict__ bcT,
    const float* __restrict__ A_log, const float* __restrict__ hin)
{
    __shared__ float red[4][16 * 65];
    const int wid  = __builtin_amdgcn_readfirstlane(
                        (int)((blockIdx.x * 256 + threadIdx.x) >> 6));
    const int lane = threadIdx.x & 63;
    const int c  = wid & (NC - 1);
    const int bd = wid >> 3;
    const int b  = bd / DI;
    const int d  = bd - b * DI;

    const float An = -expf(A_log[d * DS + lane]) * LOG2E;
    float* dtp = dtsT + (size_t)bd * SEQ + c * TCH;        // wave-uniform
    const float* up  = uT  + (size_t)bd * SEQ + c * TCH;   // wave-uniform
    const float* Bp  = bcT + ((size_t)b * 128 + lane) * SEQ + c * TCH;
    const float* Cp  = Bp + (size_t)64 * SEQ;
    float* slab = &red[threadIdx.x >> 6][0];
    const int tt = lane & 15, seg = lane >> 4;

    float4 Bc[4], Cc[4], Bn[4], Cn[4];
#pragma unroll
    for (int g = 0; g < 4; g++) {
        Bc[g] = *(const float4*)(Bp + 4 * g);
        Cc[g] = *(const float4*)(Cp + 4 * g);
    }

    float h = hin[(size_t)wid * DS + lane];
    for (int tb = 0; tb < TCH; tb += 16) {
        if (tb + 16 < TCH) {
#pragma unroll
            for (int g = 0; g < 4; g++) {
                Bn[g] = *(const float4*)(Bp + tb + 16 + 4 * g);
                Cn[g] = *(const float4*)(Cp + tb + 16 + 4 * g);
            }
        }
        float p[16];
#pragma unroll
        for (int g = 0; g < 4; g++) {
            const float4 dt4 = *(const float4*)(dtp + tb + 4 * g);
            const float4 u4  = *(const float4*)(up  + tb + 4 * g);
            h = fmaf(exp2f(dt4.x * An), h, (dt4.x * u4.x) * Bc[g].x); p[4*g+0] = h * Cc[g].x;
            h = fmaf(exp2f(dt4.y * An), h, (dt4.y * u4.y) * Bc[g].y); p[4*g+1] = h * Cc[g].y;
            h = fmaf(exp2f(dt4.z * An), h, (dt4.z * u4.z) * Bc[g].z); p[4*g+2] = h * Cc[g].z;
            h = fmaf(exp2f(dt4.w * An), h, (dt4.w * u4.w) * Bc[g].w); p[4*g+3] = h * Cc[g].w;
        }
        // wave-synchronous LDS transpose-reduce over the 64 states
#pragma unroll
        for (int i = 0; i < 16; i++) slab[i * 65 + lane] = p[i];
        float s = 0.f;
#pragma unroll
        for (int j = 0; j < 16; j++) s += slab[tt * 65 + seg * 16 + j];
        s += __shfl_xor(s, 16, 64);
        s += __shfl_xor(s, 32, 64);
        if (lane < 16) dtp[tb + tt] = s;   // coalesced 16-lane store, in place
#pragma unroll
        for (int g = 0; g < 4; g++) { Bc[g] = Bn[g]; Cc[g] = Cn[g]; }
    }
}

// Gate + transpose back: y[t][d] = (s + D*u) * silu(z), all streams coalesced.
// sT/uT read transposed via LDS; z read and y written row-major in xz.
__global__ __launch_bounds__(256) void gate_t2r(
    const float* __restrict__ sT, const float* __restrict__ uT,
    const float* __restrict__ Dskip, float* __restrict__ xz)
{
    __shared__ float ts[64][65];   // [t][d]
    __shared__ float tu[64][65];
    const int tid = threadIdx.x;
    const int d0 = blockIdx.x * 64, t0 = blockIdx.y * 64, b = blockIdx.z;
    const int cl = tid & 63, q = tid >> 6;
#pragma unroll
    for (int i = 0; i < 16; i++) {
        const int d = q * 16 + i;
        const size_t off = ((size_t)b * DI + d0 + d) * SEQ + t0 + cl;
        ts[cl][d] = sT[off];
        tu[cl][d] = uT[off];
    }
    __syncthreads();
    const float Dd = Dskip[d0 + cl];
#pragma unroll
    for (int i = 0; i < 16; i++) {
        const int t = q * 16 + i;
        const size_t row = (size_t)b * SEQ + t0 + t;
        const float z = xz[row * (2 * DI) + DI + d0 + cl];
        const float y = (ts[t][cl] + Dd * tu[t][cl]) * silu_fast(z);
        xz[row * (2 * DI) + d0 + cl] = y;
    }
}

extern "C" void kernel_launch(void* const* d_in, const int* in_sizes, int n_in,
                              void* d_out, int out_size, void* d_ws, size_t ws_size,
                              hipStream_t stream) {
    (void)in_sizes; (void)n_in; (void)out_size; (void)ws_size;
    const float* x    = (const float*)d_in[0];
    const float* Wi   = (const float*)d_in[1];
    const float* cw   = (const float*)d_in[2];
    const float* cb   = (const float*)d_in[3];
    const float* Wx   = (const float*)d_in[4];
    const float* Wdt  = (const float*)d_in[5];
    const float* bdt  = (const float*)d_in[6];
    const float* Alog = (const float*)d_in[7];
    const float* Dsk  = (const float*)d_in[8];
    const float* Wo   = (const float*)d_in[9];
    float* out = (float*)d_out;

    // Workspace (fp32), ~236 MB:
    float* xz    = (float*)d_ws;                          // [MROWS, 3072]
    float* uT    = xz    + (size_t)MROWS * (2 * DI);      // [B*DI, SEQ]
    float* dtT   = uT    + (size_t)MROWS * DI;            // [B*DI, SEQ]; becomes sT in phase3
    float* xdbl  = dtT   + (size_t)MROWS * DI;            // [MROWS, 176]
    float* bcT   = xdbl  + (size_t)MROWS * XDC;           // [B*128, SEQ]
    float* xnext = bcT   + (size_t)BATCH * 128 * SEQ;     // [MROWS, 768]
    // hend/prodA alias xnext: disjoint lifetimes (scan runs strictly between
    // the consume of xnext (layer-2 GEMM 1) and the produce (layer-1 GEMM 10)).
    float* hend  = xnext;                                 // [B*DI*NC, DS]
    float* prodA = xnext + (size_t)BATCH * DI * NC * DS;  // [B*DI*NC, DS]

    const float* src = x;
    for (int i = 0; i < DEPTH; i++) {
        const float* Wi_l   = Wi   + (size_t)i * 2 * DI * DM;
        const float* cw_l   = cw   + (size_t)i * DI * DC;
        const float* cb_l   = cb   + (size_t)i * DI;
        const float* Wx_l   = Wx   + (size_t)i * XDC * DI;
        const float* Wdt_l  = Wdt  + (size_t)i * DI * DTR;
        const float* bdt_l  = bdt  + (size_t)i * DI;
        const float* Alog_l = Alog + (size_t)i * DI * DS;
        const float* Dsk_l  = Dsk  + (size_t)i * DI;
        const float* Wo_l   = Wo   + (size_t)i * DM * DI;
        float* dst = (i == DEPTH - 1) ? out : xnext;

        // 1. xz = src @ Wi^T                       [8192, 3072]
        gemm_nt<0><<<dim3(2 * DI / 128, MROWS / 128), 256, 0, stream>>>(
            src, DM, Wi_l, nullptr, xz, 2 * DI, 2 * DI, DM);
        // 2. uT = silu(conv(xz[:, :DI])) transposed [b][d][t]
        conv_silu_T<<<dim3(DI / 64, SEQ / 64, BATCH), 256, 0, stream>>>(
            xz, cw_l, cb_l, uT);
        // 3. xdbl = u @ Wx^T via k-major uT        [8192, 176]
        gemm_tn<<<dim3((XDC + 127) / 128, MROWS / 128), 256, 0, stream>>>(
            uT, Wx_l, xdbl, XDC, XDC, DI);
        // 4. B/C transpose -> bcT [b][0:64=B,64:128=C][t]
        trans_r2t<<<dim3(2, SEQ / 64, BATCH), 256, 0, stream>>>(
            xdbl, XDC, DTR, bcT, 128);
        // 5. dt = softplus(xdbl[:, :48] @ Wdt^T + bdt) -> xz[:, 0:DI] (x-half dead)
        gemm_nt<1><<<dim3(DI / 128, MROWS / 128), 256, 0, stream>>>(
            xdbl, XDC, Wdt_l, bdt_l, xz, 2 * DI, DI, DTR);
        // 6. dt transpose -> dtT [b][d][t]
        trans_r2t<<<dim3(DI / 64, SEQ / 64, BATCH), 256, 0, stream>>>(
            xz, 2 * DI, 0, dtT, DI);
        // 7-9. chunked scan; phase3 writes raw s in place over dtT
        scan_phase1<<<(BATCH * DI * NC) / 4, 256, 0, stream>>>(
            dtT, uT, bcT, Alog_l, hend, prodA);
        scan_phase2<<<(BATCH * DI) / 4, 256, 0, stream>>>(hend, prodA);
        scan_phase3<<<(BATCH * DI * NC) / 4, 256, 0, stream>>>(
            dtT, uT, bcT, Alog_l, prodA);
        // 10. gate + transpose: y -> xz[:, :DI] row-major
        gate_t2r<<<dim3(DI / 64, SEQ / 64, BATCH), 256, 0, stream>>>(
            dtT, uT, Dsk_l, xz);
        // 11. dst = y @ Wo^T                       [8192, 768]
        gemm_nt<0><<<dim3(DM / 128, MROWS / 128), 256, 0, stream>>>(
            xz, 2 * DI, Wo_l, nullptr, dst, DM, DM, DI);

        src = dst;
    }
}

// Round 6
// 3595.689 us; speedup vs baseline: 1.3345x; 1.3345x over previous
//
#include <hip/hip_runtime.h>
#include <hip/hip_bf16.h>
#include <math.h>

// Problem constants (MambaStack reference)
#define DEPTH   2
#define DM      768      // d_model
#define DS      64       // d_state
#define DC      4        // d_conv
#define DI      1536     // d_inner
#define DTR     48       // dt_rank
#define BATCH   4
#define SEQ     2048
#define MROWS   (BATCH*SEQ)          // 8192
#define XDC     (DTR + 2*DS)         // 176 (xdbl cols)
#define NC      8                    // scan chunks
#define TCH     (SEQ/NC)             // 256 timesteps per chunk
#define LOG2E   1.44269504088896f

__device__ __forceinline__ float silu_fast(float x) {
    return x / (1.f + __expf(-x));
}
__device__ __forceinline__ float softplus_acc(float x) {
    return x > 20.f ? x : log1pf(expf(x));
}

// C[M,N] = A[M,K] (row-major, ldA) @ W[N,K]^T  (W row-major, ld = K)
// EPI: 0 = none, 1 = softplus(x + bias[col])
template<int EPI>
__global__ __launch_bounds__(256, 2) void gemm_nt(
    const float* __restrict__ A, int ldA,
    const float* __restrict__ W,
    const float* __restrict__ bias,
    float* __restrict__ C, int ldC,
    int N, int K)
{
    __shared__ float As[8][132];
    __shared__ float Bs[8][132];
    const int tid = threadIdx.x;
    const int bm0 = blockIdx.y * 128;
    const int bn0 = blockIdx.x * 128;
    const int tx = tid & 15;
    const int ty = tid >> 4;
    const int lrow = tid >> 1;
    const int lk4  = (tid & 1) * 4;

    float acc[8][8];
#pragma unroll
    for (int i = 0; i < 8; i++)
#pragma unroll
        for (int j = 0; j < 8; j++) acc[i][j] = 0.f;

    for (int k0 = 0; k0 < K; k0 += 8) {
        const float4 av = *(const float4*)(A + (size_t)(bm0 + lrow) * ldA + (k0 + lk4));
        float4 wv;
        const int wrow = bn0 + lrow;
        if (wrow < N) wv = *(const float4*)(W + (size_t)wrow * K + (k0 + lk4));
        else          wv = make_float4(0.f, 0.f, 0.f, 0.f);
        __syncthreads();
        As[lk4 + 0][lrow] = av.x; As[lk4 + 1][lrow] = av.y;
        As[lk4 + 2][lrow] = av.z; As[lk4 + 3][lrow] = av.w;
        Bs[lk4 + 0][lrow] = wv.x; Bs[lk4 + 1][lrow] = wv.y;
        Bs[lk4 + 2][lrow] = wv.z; Bs[lk4 + 3][lrow] = wv.w;
        __syncthreads();
#pragma unroll
        for (int kk = 0; kk < 8; kk++) {
            const float4 a0 = *(const float4*)&As[kk][ty * 8];
            const float4 a1 = *(const float4*)&As[kk][ty * 8 + 4];
            const float4 b0 = *(const float4*)&Bs[kk][tx * 8];
            const float4 b1 = *(const float4*)&Bs[kk][tx * 8 + 4];
            const float ar[8] = {a0.x, a0.y, a0.z, a0.w, a1.x, a1.y, a1.z, a1.w};
            const float br[8] = {b0.x, b0.y, b0.z, b0.w, b1.x, b1.y, b1.z, b1.w};
#pragma unroll
            for (int i = 0; i < 8; i++)
#pragma unroll
                for (int j = 0; j < 8; j++)
                    acc[i][j] = fmaf(ar[i], br[j], acc[i][j]);
        }
    }

#pragma unroll
    for (int i = 0; i < 8; i++) {
        const int row = bm0 + ty * 8 + i;
#pragma unroll
        for (int j4 = 0; j4 < 8; j4 += 4) {
            const int col = bn0 + tx * 8 + j4;
            if (col + 3 < N) {
                float4 v = make_float4(acc[i][j4], acc[i][j4 + 1], acc[i][j4 + 2], acc[i][j4 + 3]);
                if (EPI == 1) {
                    v.x = softplus_acc(v.x + bias[col + 0]);
                    v.y = softplus_acc(v.y + bias[col + 1]);
                    v.z = softplus_acc(v.z + bias[col + 2]);
                    v.w = softplus_acc(v.w + bias[col + 3]);
                }
                *(float4*)(C + (size_t)row * ldC + col) = v;
            }
        }
    }
}

// C[M,N] = A @ W^T where A is given K-MAJOR per batch: AT[(b*K + k)*SEQ + t].
__global__ __launch_bounds__(256, 2) void gemm_tn(
    const float* __restrict__ AT,
    const float* __restrict__ W,
    float* __restrict__ C, int ldC,
    int N, int K)
{
    __shared__ float As[8][132];
    __shared__ float Bs[8][132];
    const int tid = threadIdx.x;
    const int bm0 = blockIdx.y * 128;
    const int bn0 = blockIdx.x * 128;
    const int bb  = bm0 / SEQ;
    const int t0  = bm0 - bb * SEQ;
    const int tx = tid & 15;
    const int ty = tid >> 4;
    const int arow = tid >> 5;          // k row 0..7
    const int am4  = (tid & 31) * 4;    // m offset 0..124
    const int lrow = tid >> 1;
    const int lk4  = (tid & 1) * 4;

    float acc[8][8];
#pragma unroll
    for (int i = 0; i < 8; i++)
#pragma unroll
        for (int j = 0; j < 8; j++) acc[i][j] = 0.f;

    for (int k0 = 0; k0 < K; k0 += 8) {
        const float4 av = *(const float4*)(AT + ((size_t)(bb * K + k0 + arow)) * SEQ + t0 + am4);
        float4 wv;
        const int wrow = bn0 + lrow;
        if (wrow < N) wv = *(const float4*)(W + (size_t)wrow * K + (k0 + lk4));
        else          wv = make_float4(0.f, 0.f, 0.f, 0.f);
        __syncthreads();
        *(float4*)&As[arow][am4] = av;
        Bs[lk4 + 0][lrow] = wv.x; Bs[lk4 + 1][lrow] = wv.y;
        Bs[lk4 + 2][lrow] = wv.z; Bs[lk4 + 3][lrow] = wv.w;
        __syncthreads();
#pragma unroll
        for (int kk = 0; kk < 8; kk++) {
            const float4 a0 = *(const float4*)&As[kk][ty * 8];
            const float4 a1 = *(const float4*)&As[kk][ty * 8 + 4];
            const float4 b0 = *(const float4*)&Bs[kk][tx * 8];
            const float4 b1 = *(const float4*)&Bs[kk][tx * 8 + 4];
            const float ar[8] = {a0.x, a0.y, a0.z, a0.w, a1.x, a1.y, a1.z, a1.w};
            const float br[8] = {b0.x, b0.y, b0.z, b0.w, b1.x, b1.y, b1.z, b1.w};
#pragma unroll
            for (int i = 0; i < 8; i++)
#pragma unroll
                for (int j = 0; j < 8; j++)
                    acc[i][j] = fmaf(ar[i], br[j], acc[i][j]);
        }
    }

#pragma unroll
    for (int i = 0; i < 8; i++) {
        const int row = bm0 + ty * 8 + i;
#pragma unroll
        for (int j4 = 0; j4 < 8; j4 += 4) {
            const int col = bn0 + tx * 8 + j4;
            if (col + 3 < N) {
                *(float4*)(C + (size_t)row * ldC + col) =
                    make_float4(acc[i][j4], acc[i][j4 + 1], acc[i][j4 + 2], acc[i][j4 + 3]);
            }
        }
    }
}

// Depthwise causal conv (K=4) + SiLU -> uT [b][d][t] only.
__global__ __launch_bounds__(256) void conv_silu_T(
    const float* __restrict__ xz, const float* __restrict__ cw,
    const float* __restrict__ cb, float* __restrict__ uT)
{
    __shared__ float tin[67][65];   // [t(-3..63)][d], +1 pad
    __shared__ float ttr[64][65];   // [d][t], +1 pad
    const int tid = threadIdx.x;
    const int d0 = blockIdx.x * 64, t0 = blockIdx.y * 64, b = blockIdx.z;
    const int cl = tid & 63, q = tid >> 6;

    for (int r = q; r < 67; r += 4) {
        const int t = t0 - 3 + r;
        float v = 0.f;
        if (t >= 0) v = xz[((size_t)b * SEQ + t) * (2 * DI) + d0 + cl];
        tin[r][cl] = v;
    }
    __syncthreads();

    const float4 w = ((const float4*)cw)[d0 + cl];
    const float bb = cb[d0 + cl];
#pragma unroll
    for (int i = 0; i < 16; i++) {
        const int t = q * 16 + i;
        float a = bb;
        a = fmaf(tin[t + 0][cl], w.x, a);
        a = fmaf(tin[t + 1][cl], w.y, a);
        a = fmaf(tin[t + 2][cl], w.z, a);
        a = fmaf(tin[t + 3][cl], w.w, a);
        ttr[cl][t] = silu_fast(a);
    }
    __syncthreads();
#pragma unroll
    for (int i = 0; i < 16; i++) {
        const int d = q * 16 + i;
        uT[((size_t)b * DI + d0 + d) * SEQ + t0 + cl] = ttr[d][cl];  // coalesced in t
    }
}

// Tiled transpose: in[row=b*SEQ+t, coloff+c] (ld ldin) -> out[(b*ncols+c)*SEQ + t]
__global__ __launch_bounds__(256) void trans_r2t(
    const float* __restrict__ in, int ldin, int coloff,
    float* __restrict__ out, int ncols)
{
    __shared__ float tile[64][65];
    const int tid = threadIdx.x;
    const int c0 = blockIdx.x * 64, t0 = blockIdx.y * 64, b = blockIdx.z;
    const int cl = tid & 63, q = tid >> 6;
#pragma unroll
    for (int i = 0; i < 16; i++) {
        const int r = q * 16 + i;
        tile[r][cl] = in[((size_t)b * SEQ + t0 + r) * ldin + coloff + c0 + cl];
    }
    __syncthreads();
#pragma unroll
    for (int i = 0; i < 16; i++) {
        const int cc = q * 16 + i;
        out[((size_t)b * ncols + c0 + cc) * SEQ + t0 + cl] = tile[cl][cc];
    }
}

// B/C transpose into the lane-interleaved layout the scan consumes:
//   bc4[(b*(SEQ/4) + t/4)*128 + ch] = float4{ x[t..t+3][ch] }   (ch 0..127)
// One float4 per lane, lane=ch fastest axis -> coalesced 1KB loads in the scan.
__global__ __launch_bounds__(256) void trans_bc_i4(
    const float* __restrict__ in,      // xdbl
    float4* __restrict__ bc4)
{
    __shared__ float tile[64][65];     // [t][ch]
    const int tid = threadIdx.x;
    const int c0 = blockIdx.x * 64, t0 = blockIdx.y * 64, b = blockIdx.z;
    const int cl = tid & 63, q = tid >> 6;
#pragma unroll
    for (int i = 0; i < 16; i++) {
        const int r = q * 16 + i;
        tile[r][cl] = in[((size_t)b * SEQ + t0 + r) * XDC + DTR + c0 + cl];
    }
    __syncthreads();
#pragma unroll
    for (int i = 0; i < 4; i++) {
        const int j = q * 4 + i;       // t4 group within tile (0..15)
        const float4 v = make_float4(tile[4 * j + 0][cl], tile[4 * j + 1][cl],
                                     tile[4 * j + 2][cl], tile[4 * j + 3][cl]);
        bc4[((size_t)b * (SEQ / 4) + (t0 / 4 + j)) * 128 + c0 + cl] = v;
    }
}

// ---------------- Chunked selective scan ----------------
// dtT/uT are [b][d][t]: wave-uniform float4 loads.  B/C come from the
// interleaved bc4 layout: one coalesced dwordx4 per lane per 4 timesteps.

// Phase 1: per (b,d,chunk) wave; computes chunk-local h_end and decay product.
__global__ __launch_bounds__(256, 4) void scan_phase1(
    const float* __restrict__ dtT, const float* __restrict__ uT,
    const float4* __restrict__ bc4, const float* __restrict__ A_log,
    float* __restrict__ hend, float* __restrict__ prodA)
{
    const int wid  = __builtin_amdgcn_readfirstlane(
                        (int)((blockIdx.x * 256 + threadIdx.x) >> 6));
    const int lane = threadIdx.x & 63;
    const int c  = wid & (NC - 1);
    const int bd = wid >> 3;
    const int b  = bd / DI;
    const int d  = bd - b * DI;

    const float An = -expf(A_log[d * DS + lane]) * LOG2E;
    const float* dtp = dtT + (size_t)bd * SEQ + c * TCH;   // wave-uniform
    const float* up  = uT  + (size_t)bd * SEQ + c * TCH;   // wave-uniform
    const float4* Bp = bc4 + ((size_t)b * (SEQ / 4) + c * (TCH / 4)) * 128 + lane;

    float4 Bc[4], Bn[4];
#pragma unroll
    for (int g = 0; g < 4; g++) Bc[g] = Bp[(size_t)g * 128];

    float h = 0.f, sdt = 0.f;
    for (int tb = 0; tb < TCH; tb += 16) {
        if (tb + 16 < TCH) {
#pragma unroll
            for (int g = 0; g < 4; g++)
                Bn[g] = Bp[(size_t)(tb / 4 + 4 + g) * 128];
        }
#pragma unroll
        for (int g = 0; g < 4; g++) {
            const float4 dt4 = *(const float4*)(dtp + tb + 4 * g);
            const float4 u4  = *(const float4*)(up  + tb + 4 * g);
            h = fmaf(exp2f(dt4.x * An), h, (dt4.x * u4.x) * Bc[g].x); sdt += dt4.x;
            h = fmaf(exp2f(dt4.y * An), h, (dt4.y * u4.y) * Bc[g].y); sdt += dt4.y;
            h = fmaf(exp2f(dt4.z * An), h, (dt4.z * u4.z) * Bc[g].z); sdt += dt4.z;
            h = fmaf(exp2f(dt4.w * An), h, (dt4.w * u4.w) * Bc[g].w); sdt += dt4.w;
        }
#pragma unroll
        for (int g = 0; g < 4; g++) Bc[g] = Bn[g];
    }
    hend [(size_t)wid * DS + lane] = h;
    prodA[(size_t)wid * DS + lane] = exp2f(An * sdt);
}

// Phase 2: per (b,d) wave, serial over chunks; writes h_in into prodA in place.
__global__ __launch_bounds__(256) void scan_phase2(
    float* __restrict__ hend, float* __restrict__ prodA)
{
    const int bd   = (blockIdx.x * 256 + threadIdx.x) >> 6;
    const int lane = threadIdx.x & 63;
    float h = 0.f;
#pragma unroll
    for (int c = 0; c < NC; c++) {
        const size_t off = ((size_t)bd * NC + c) * DS + lane;
        const float pA = prodA[off];
        const float he = hend[off];
        prodA[off] = h;
        h = fmaf(pA, h, he);
    }
}

// Phase 3: resumed scan; writes raw reduced s IN PLACE over dtT (each wave
// reads dt[t] strictly before writing s[t]; per-wave spans are disjoint).
__global__ __launch_bounds__(256, 4) void scan_phase3(
    float* dtsT,                                   // in: dtT, out: sT (aliased!)
    const float* __restrict__ uT, const float4* __restrict__ bc4,
    const float* __restrict__ A_log, const float* __restrict__ hin)
{
    __shared__ float red[4][16 * 65];
    const int wid  = __builtin_amdgcn_readfirstlane(
                        (int)((blockIdx.x * 256 + threadIdx.x) >> 6));
    const int lane = threadIdx.x & 63;
    const int c  = wid & (NC - 1);
    const int bd = wid >> 3;
    const int b  = bd / DI;
    const int d  = bd - b * DI;

    const float An = -expf(A_log[d * DS + lane]) * LOG2E;
    float* dtp = dtsT + (size_t)bd * SEQ + c * TCH;        // wave-uniform
    const float* up  = uT  + (size_t)bd * SEQ + c * TCH;   // wave-uniform
    const float4* Bp = bc4 + ((size_t)b * (SEQ / 4) + c * (TCH / 4)) * 128 + lane;
    const float4* Cp = Bp + 64;
    float* slab = &red[threadIdx.x >> 6][0];
    const int tt = lane & 15, seg = lane >> 4;

    float4 Bc[4], Cc[4], Bn[4], Cn[4];
#pragma unroll
    for (int g = 0; g < 4; g++) {
        Bc[g] = Bp[(size_t)g * 128];
        Cc[g] = Cp[(size_t)g * 128];
    }

    float h = hin[(size_t)wid * DS + lane];
    for (int tb = 0; tb < TCH; tb += 16) {
        if (tb + 16 < TCH) {
#pragma unroll
            for (int g = 0; g < 4; g++) {
                Bn[g] = Bp[(size_t)(tb / 4 + 4 + g) * 128];
                Cn[g] = Cp[(size_t)(tb / 4 + 4 + g) * 128];
            }
        }
        float p[16];
#pragma unroll
        for (int g = 0; g < 4; g++) {
            const float4 dt4 = *(const float4*)(dtp + tb + 4 * g);
            const float4 u4  = *(const float4*)(up  + tb + 4 * g);
            h = fmaf(exp2f(dt4.x * An), h, (dt4.x * u4.x) * Bc[g].x); p[4*g+0] = h * Cc[g].x;
            h = fmaf(exp2f(dt4.y * An), h, (dt4.y * u4.y) * Bc[g].y); p[4*g+1] = h * Cc[g].y;
            h = fmaf(exp2f(dt4.z * An), h, (dt4.z * u4.z) * Bc[g].z); p[4*g+2] = h * Cc[g].z;
            h = fmaf(exp2f(dt4.w * An), h, (dt4.w * u4.w) * Bc[g].w); p[4*g+3] = h * Cc[g].w;
        }
        // wave-synchronous LDS transpose-reduce over the 64 states
#pragma unroll
        for (int i = 0; i < 16; i++) slab[i * 65 + lane] = p[i];
        float s = 0.f;
#pragma unroll
        for (int j = 0; j < 16; j++) s += slab[tt * 65 + seg * 16 + j];
        s += __shfl_xor(s, 16, 64);
        s += __shfl_xor(s, 32, 64);
        if (lane < 16) dtp[tb + tt] = s;   // coalesced 16-lane store, in place
#pragma unroll
        for (int g = 0; g < 4; g++) { Bc[g] = Bn[g]; Cc[g] = Cn[g]; }
    }
}

// Gate + transpose back: y[t][d] = (s + D*u) * silu(z), all streams coalesced.
__global__ __launch_bounds__(256) void gate_t2r(
    const float* __restrict__ sT, const float* __restrict__ uT,
    const float* __restrict__ Dskip, float* __restrict__ xz)
{
    __shared__ float ts[64][65];   // [t][d]
    __shared__ float tu[64][65];
    const int tid = threadIdx.x;
    const int d0 = blockIdx.x * 64, t0 = blockIdx.y * 64, b = blockIdx.z;
    const int cl = tid & 63, q = tid >> 6;
#pragma unroll
    for (int i = 0; i < 16; i++) {
        const int d = q * 16 + i;
        const size_t off = ((size_t)b * DI + d0 + d) * SEQ + t0 + cl;
        ts[cl][d] = sT[off];
        tu[cl][d] = uT[off];
    }
    __syncthreads();
    const float Dd = Dskip[d0 + cl];
#pragma unroll
    for (int i = 0; i < 16; i++) {
        const int t = q * 16 + i;
        const size_t row = (size_t)b * SEQ + t0 + t;
        const float z = xz[row * (2 * DI) + DI + d0 + cl];
        const float y = (ts[t][cl] + Dd * tu[t][cl]) * silu_fast(z);
        xz[row * (2 * DI) + d0 + cl] = y;
    }
}

extern "C" void kernel_launch(void* const* d_in, const int* in_sizes, int n_in,
                              void* d_out, int out_size, void* d_ws, size_t ws_size,
                              hipStream_t stream) {
    (void)in_sizes; (void)n_in; (void)out_size; (void)ws_size;
    const float* x    = (const float*)d_in[0];
    const float* Wi   = (const float*)d_in[1];
    const float* cw   = (const float*)d_in[2];
    const float* cb   = (const float*)d_in[3];
    const float* Wx   = (const float*)d_in[4];
    const float* Wdt  = (const float*)d_in[5];
    const float* bdt  = (const float*)d_in[6];
    const float* Alog = (const float*)d_in[7];
    const float* Dsk  = (const float*)d_in[8];
    const float* Wo   = (const float*)d_in[9];
    float* out = (float*)d_out;

    // Workspace (fp32), ~236 MB:
    float* xz    = (float*)d_ws;                          // [MROWS, 3072]
    float* uT    = xz    + (size_t)MROWS * (2 * DI);      // [B*DI, SEQ]
    float* dtT   = uT    + (size_t)MROWS * DI;            // [B*DI, SEQ]; becomes sT in phase3
    float* xdbl  = dtT   + (size_t)MROWS * DI;            // [MROWS, 176]
    float* bcT   = xdbl  + (size_t)MROWS * XDC;           // [B][SEQ/4][128][4] interleaved
    float* xnext = bcT   + (size_t)BATCH * 128 * SEQ;     // [MROWS, 768]
    // hend/prodA alias xnext: disjoint lifetimes (scan runs strictly between
    // the consume of xnext (layer-2 GEMM 1) and the produce (layer-1 GEMM 11)).
    float* hend  = xnext;                                 // [B*DI*NC, DS]
    float* prodA = xnext + (size_t)BATCH * DI * NC * DS;  // [B*DI*NC, DS]

    const float* src = x;
    for (int i = 0; i < DEPTH; i++) {
        const float* Wi_l   = Wi   + (size_t)i * 2 * DI * DM;
        const float* cw_l   = cw   + (size_t)i * DI * DC;
        const float* cb_l   = cb   + (size_t)i * DI;
        const float* Wx_l   = Wx   + (size_t)i * XDC * DI;
        const float* Wdt_l  = Wdt  + (size_t)i * DI * DTR;
        const float* bdt_l  = bdt  + (size_t)i * DI;
        const float* Alog_l = Alog + (size_t)i * DI * DS;
        const float* Dsk_l  = Dsk  + (size_t)i * DI;
        const float* Wo_l   = Wo   + (size_t)i * DM * DI;
        float* dst = (i == DEPTH - 1) ? out : xnext;

        // 1. xz = src @ Wi^T                       [8192, 3072]
        gemm_nt<0><<<dim3(2 * DI / 128, MROWS / 128), 256, 0, stream>>>(
            src, DM, Wi_l, nullptr, xz, 2 * DI, 2 * DI, DM);
        // 2. uT = silu(conv(xz[:, :DI])) transposed [b][d][t]
        conv_silu_T<<<dim3(DI / 64, SEQ / 64, BATCH), 256, 0, stream>>>(
            xz, cw_l, cb_l, uT);
        // 3. xdbl = u @ Wx^T via k-major uT        [8192, 176]
        gemm_tn<<<dim3((XDC + 127) / 128, MROWS / 128), 256, 0, stream>>>(
            uT, Wx_l, xdbl, XDC, XDC, DI);
        // 4. B/C -> lane-interleaved bc4 layout
        trans_bc_i4<<<dim3(2, SEQ / 64, BATCH), 256, 0, stream>>>(
            xdbl, (float4*)bcT);
        // 5. dt = softplus(xdbl[:, :48] @ Wdt^T + bdt) -> xz[:, 0:DI] (x-half dead)
        gemm_nt<1><<<dim3(DI / 128, MROWS / 128), 256, 0, stream>>>(
            xdbl, XDC, Wdt_l, bdt_l, xz, 2 * DI, DI, DTR);
        // 6. dt transpose -> dtT [b][d][t]
        trans_r2t<<<dim3(DI / 64, SEQ / 64, BATCH), 256, 0, stream>>>(
            xz, 2 * DI, 0, dtT, DI);
        // 7-9. chunked scan; phase3 writes raw s in place over dtT
        scan_phase1<<<(BATCH * DI * NC) / 4, 256, 0, stream>>>(
            dtT, uT, (const float4*)bcT, Alog_l, hend, prodA);
        scan_phase2<<<(BATCH * DI) / 4, 256, 0, stream>>>(hend, prodA);
        scan_phase3<<<(BATCH * DI * NC) / 4, 256, 0, stream>>>(
            dtT, uT, (const float4*)bcT, Alog_l, prodA);
        // 10. gate + transpose: y -> xz[:, :DI] row-major
        gate_t2r<<<dim3(DI / 64, SEQ / 64, BATCH), 256, 0, stream>>>(
            dtT, uT, Dsk_l, xz);
        // 11. dst = y @ Wo^T                       [8192, 768]
        gemm_nt<0><<<dim3(DM / 128, MROWS / 128), 256, 0, stream>>>(
            xz, 2 * DI, Wo_l, nullptr, dst, DM, DM, DI);

        src = dst;
    }
}

// Round 7
// 2482.206 us; speedup vs baseline: 1.9332x; 1.4486x over previous
//
#include <hip/hip_runtime.h>
#include <hip/hip_bf16.h>
#include <math.h>

// Problem constants (MambaStack reference)
#define DEPTH   2
#define DM      768      // d_model
#define DS      64       // d_state
#define DC      4        // d_conv
#define DI      1536     // d_inner
#define DTR     48       // dt_rank
#define BATCH   4
#define SEQ     2048
#define MROWS   (BATCH*SEQ)          // 8192
#define XDC     (DTR + 2*DS)         // 176 (xdbl cols)
#define NC      8                    // scan chunks
#define TCH     (SEQ/NC)             // 256 timesteps per chunk
#define LOG2E   1.44269504088896f

typedef __attribute__((ext_vector_type(8))) short bf16x8;
typedef __attribute__((ext_vector_type(4))) float f32x4;
typedef unsigned short ushort_t;
#define GAS __attribute__((address_space(1)))
#define LAS __attribute__((address_space(3)))

__device__ __forceinline__ float silu_fast(float x) {
    return x / (1.f + __expf(-x));
}
__device__ __forceinline__ float softplus_acc(float x) {
    return x > 20.f ? x : log1pf(expf(x));
}

// Split fp32 -> (hi, lo) bf16 pair, both RNE.  hi+lo represents f to ~2^-17.
__device__ __forceinline__ void bf16_split(float f, ushort_t& h, ushort_t& l) {
    unsigned u = __float_as_uint(f);
    unsigned hr = u + 0x7FFF + ((u >> 16) & 1);
    h = (ushort_t)(hr >> 16);
    float lof = f - __uint_as_float((unsigned)h << 16);
    unsigned ul = __float_as_uint(lof);
    unsigned lr = ul + 0x7FFF + ((ul >> 16) & 1);
    l = (ushort_t)(lr >> 16);
}

// Contiguous fp32 array -> hi/lo bf16 planes.  n multiple of 1024.
__global__ __launch_bounds__(256) void split_bf16(
    const float* __restrict__ in, ushort_t* __restrict__ hi,
    ushort_t* __restrict__ lo)
{
    const size_t i = ((size_t)blockIdx.x * 256 + threadIdx.x) * 4;
    const float4 v = *(const float4*)(in + i);
    ushort4 h, l;
    bf16_split(v.x, h.x, l.x); bf16_split(v.y, h.y, l.y);
    bf16_split(v.z, h.z, l.z); bf16_split(v.w, h.w, l.w);
    *(ushort4*)(hi + i) = h;
    *(ushort4*)(lo + i) = l;
}

// y (= xz[:, 0:DI], ld 2*DI) -> hi/lo bf16 planes [MROWS, DI].
__global__ __launch_bounds__(256) void split_bf16_y(
    const float* __restrict__ xz, ushort_t* __restrict__ hi,
    ushort_t* __restrict__ lo)
{
    const size_t i = ((size_t)blockIdx.x * 256 + threadIdx.x) * 4;  // over MROWS*DI
    const size_t row = i / DI, col = i - row * DI;
    const float4 v = *(const float4*)(xz + row * (2 * DI) + col);
    ushort4 h, l;
    bf16_split(v.x, h.x, l.x); bf16_split(v.y, h.y, l.y);
    bf16_split(v.z, h.z, l.z); bf16_split(v.w, h.w, l.w);
    *(ushort4*)(hi + i) = h;
    *(ushort4*)(lo + i) = l;
}

// ---------------- bf16x2-split MFMA GEMM ----------------
// C[M,N] = (Ah+Al)[M,K] @ (Wh+Wl)[N,K]^T, planes bf16 row-major, C fp32.
// 128x128 tile, BK=32, 256 threads = 4 waves (2x2), each wave 64x64 via
// 4x4 grid of 16x16x32 MFMA tiles; 3 MFMAs per tile (hh, hl, lh).
// M,K mult of 32/128 as needed; N mult of 128.  Staging: wave w stages
// plane w via global_load_lds dwordx4 (8 instrs -> 128x32 bf16 tile).
__global__ __launch_bounds__(256, 2) void gemm_mfma(
    const ushort_t* __restrict__ Ah, const ushort_t* __restrict__ Al,
    const ushort_t* __restrict__ Wh, const ushort_t* __restrict__ Wl,
    float* __restrict__ C, int N, int K)
{
    __shared__ ushort_t lds[4][128 * 32];
    const int tid  = threadIdx.x;
    const int wave = tid >> 6, lane = tid & 63;
    const int bm0 = blockIdx.y * 128, bn0 = blockIdx.x * 128;
    const int wm = (wave >> 1) * 64, wn = (wave & 1) * 64;

    const ushort_t* gp = (wave == 0) ? Ah : (wave == 1) ? Al : (wave == 2) ? Wh : Wl;
    const int rb = (wave < 2) ? bm0 : bn0;
    const int srow = lane >> 2;           // 0..15
    const int skq  = (lane & 3) * 8;      // k offset in elements

    f32x4 acc[4][4];
#pragma unroll
    for (int i = 0; i < 4; i++)
#pragma unroll
        for (int j = 0; j < 4; j++) acc[i][j] = (f32x4){0.f, 0.f, 0.f, 0.f};

    const int lm  = lane & 15;
    const int kg8 = (lane >> 4) * 8;

    for (int k0 = 0; k0 < K; k0 += 32) {
#pragma unroll
        for (int j = 0; j < 8; j++) {
            const ushort_t* ga = gp + (size_t)(rb + j * 16 + srow) * K + k0 + skq;
            __builtin_amdgcn_global_load_lds(
                (const GAS unsigned*)ga, (LAS unsigned*)&lds[wave][j * 512], 16, 0, 0);
        }
        __syncthreads();

        bf16x8 ah[4], al[4], bh[4], bl[4];
#pragma unroll
        for (int i = 0; i < 4; i++) {
            const int ar = (wm + i * 16 + lm) * 32 + kg8;
            ah[i] = *(const bf16x8*)&lds[0][ar];
            al[i] = *(const bf16x8*)&lds[1][ar];
            const int br = (wn + i * 16 + lm) * 32 + kg8;
            bh[i] = *(const bf16x8*)&lds[2][br];
            bl[i] = *(const bf16x8*)&lds[3][br];
        }
#pragma unroll
        for (int mi = 0; mi < 4; mi++)
#pragma unroll
            for (int ni = 0; ni < 4; ni++) {
                f32x4 t = acc[mi][ni];
                t = __builtin_amdgcn_mfma_f32_16x16x32_bf16(al[mi], bh[ni], t, 0, 0, 0);
                t = __builtin_amdgcn_mfma_f32_16x16x32_bf16(ah[mi], bl[ni], t, 0, 0, 0);
                t = __builtin_amdgcn_mfma_f32_16x16x32_bf16(ah[mi], bh[ni], t, 0, 0, 0);
                acc[mi][ni] = t;
            }
        __syncthreads();
    }

#pragma unroll
    for (int mi = 0; mi < 4; mi++)
#pragma unroll
        for (int ni = 0; ni < 4; ni++)
#pragma unroll
            for (int r = 0; r < 4; r++) {
                const int rowg = bm0 + wm + mi * 16 + (lane >> 4) * 4 + r;
                const int colg = bn0 + wn + ni * 16 + lm;
                C[(size_t)rowg * N + colg] = acc[mi][ni][r];
            }
}

// C[M,N] = A @ W^T where A is given K-MAJOR per batch: AT[(b*K + k)*SEQ + t].
__global__ __launch_bounds__(256, 2) void gemm_tn(
    const float* __restrict__ AT,
    const float* __restrict__ W,
    float* __restrict__ C, int ldC,
    int N, int K)
{
    __shared__ float As[8][132];
    __shared__ float Bs[8][132];
    const int tid = threadIdx.x;
    const int bm0 = blockIdx.y * 128;
    const int bn0 = blockIdx.x * 128;
    const int bb  = bm0 / SEQ;
    const int t0  = bm0 - bb * SEQ;
    const int tx = tid & 15;
    const int ty = tid >> 4;
    const int arow = tid >> 5;
    const int am4  = (tid & 31) * 4;
    const int lrow = tid >> 1;
    const int lk4  = (tid & 1) * 4;

    float acc[8][8];
#pragma unroll
    for (int i = 0; i < 8; i++)
#pragma unroll
        for (int j = 0; j < 8; j++) acc[i][j] = 0.f;

    for (int k0 = 0; k0 < K; k0 += 8) {
        const float4 av = *(const float4*)(AT + ((size_t)(bb * K + k0 + arow)) * SEQ + t0 + am4);
        float4 wv;
        const int wrow = bn0 + lrow;
        if (wrow < N) wv = *(const float4*)(W + (size_t)wrow * K + (k0 + lk4));
        else          wv = make_float4(0.f, 0.f, 0.f, 0.f);
        __syncthreads();
        *(float4*)&As[arow][am4] = av;
        Bs[lk4 + 0][lrow] = wv.x; Bs[lk4 + 1][lrow] = wv.y;
        Bs[lk4 + 2][lrow] = wv.z; Bs[lk4 + 3][lrow] = wv.w;
        __syncthreads();
#pragma unroll
        for (int kk = 0; kk < 8; kk++) {
            const float4 a0 = *(const float4*)&As[kk][ty * 8];
            const float4 a1 = *(const float4*)&As[kk][ty * 8 + 4];
            const float4 b0 = *(const float4*)&Bs[kk][tx * 8];
            const float4 b1 = *(const float4*)&Bs[kk][tx * 8 + 4];
            const float ar[8] = {a0.x, a0.y, a0.z, a0.w, a1.x, a1.y, a1.z, a1.w};
            const float br[8] = {b0.x, b0.y, b0.z, b0.w, b1.x, b1.y, b1.z, b1.w};
#pragma unroll
            for (int i = 0; i < 8; i++)
#pragma unroll
                for (int j = 0; j < 8; j++)
                    acc[i][j] = fmaf(ar[i], br[j], acc[i][j]);
        }
    }

#pragma unroll
    for (int i = 0; i < 8; i++) {
        const int row = bm0 + ty * 8 + i;
#pragma unroll
        for (int j4 = 0; j4 < 8; j4 += 4) {
            const int col = bn0 + tx * 8 + j4;
            if (col + 3 < N) {
                *(float4*)(C + (size_t)row * ldC + col) =
                    make_float4(acc[i][j4], acc[i][j4 + 1], acc[i][j4 + 2], acc[i][j4 + 3]);
            }
        }
    }
}

// dt GEMM (small K=48): C = softplus(A[:, :48] @ W^T + bias), row-major.
__global__ __launch_bounds__(256, 2) void gemm_dt(
    const float* __restrict__ A, int ldA,
    const float* __restrict__ W,
    const float* __restrict__ bias,
    float* __restrict__ C, int ldC,
    int N, int K)
{
    __shared__ float As[8][132];
    __shared__ float Bs[8][132];
    const int tid = threadIdx.x;
    const int bm0 = blockIdx.y * 128;
    const int bn0 = blockIdx.x * 128;
    const int tx = tid & 15;
    const int ty = tid >> 4;
    const int lrow = tid >> 1;
    const int lk4  = (tid & 1) * 4;

    float acc[8][8];
#pragma unroll
    for (int i = 0; i < 8; i++)
#pragma unroll
        for (int j = 0; j < 8; j++) acc[i][j] = 0.f;

    for (int k0 = 0; k0 < K; k0 += 8) {
        const float4 av = *(const float4*)(A + (size_t)(bm0 + lrow) * ldA + (k0 + lk4));
        float4 wv;
        const int wrow = bn0 + lrow;
        if (wrow < N) wv = *(const float4*)(W + (size_t)wrow * K + (k0 + lk4));
        else          wv = make_float4(0.f, 0.f, 0.f, 0.f);
        __syncthreads();
        As[lk4 + 0][lrow] = av.x; As[lk4 + 1][lrow] = av.y;
        As[lk4 + 2][lrow] = av.z; As[lk4 + 3][lrow] = av.w;
        Bs[lk4 + 0][lrow] = wv.x; Bs[lk4 + 1][lrow] = wv.y;
        Bs[lk4 + 2][lrow] = wv.z; Bs[lk4 + 3][lrow] = wv.w;
        __syncthreads();
#pragma unroll
        for (int kk = 0; kk < 8; kk++) {
            const float4 a0 = *(const float4*)&As[kk][ty * 8];
            const float4 a1 = *(const float4*)&As[kk][ty * 8 + 4];
            const float4 b0 = *(const float4*)&Bs[kk][tx * 8];
            const float4 b1 = *(const float4*)&Bs[kk][tx * 8 + 4];
            const float ar[8] = {a0.x, a0.y, a0.z, a0.w, a1.x, a1.y, a1.z, a1.w};
            const float br[8] = {b0.x, b0.y, b0.z, b0.w, b1.x, b1.y, b1.z, b1.w};
#pragma unroll
            for (int i = 0; i < 8; i++)
#pragma unroll
                for (int j = 0; j < 8; j++)
                    acc[i][j] = fmaf(ar[i], br[j], acc[i][j]);
        }
    }

#pragma unroll
    for (int i = 0; i < 8; i++) {
        const int row = bm0 + ty * 8 + i;
#pragma unroll
        for (int j4 = 0; j4 < 8; j4 += 4) {
            const int col = bn0 + tx * 8 + j4;
            if (col + 3 < N) {
                float4 v = make_float4(acc[i][j4], acc[i][j4 + 1], acc[i][j4 + 2], acc[i][j4 + 3]);
                v.x = softplus_acc(v.x + bias[col + 0]);
                v.y = softplus_acc(v.y + bias[col + 1]);
                v.z = softplus_acc(v.z + bias[col + 2]);
                v.w = softplus_acc(v.w + bias[col + 3]);
                *(float4*)(C + (size_t)row * ldC + col) = v;
            }
        }
    }
}

// Depthwise causal conv (K=4) + SiLU -> uT [b][d][t] only.
__global__ __launch_bounds__(256) void conv_silu_T(
    const float* __restrict__ xz, const float* __restrict__ cw,
    const float* __restrict__ cb, float* __restrict__ uT)
{
    __shared__ float tin[67][65];
    __shared__ float ttr[64][65];
    const int tid = threadIdx.x;
    const int d0 = blockIdx.x * 64, t0 = blockIdx.y * 64, b = blockIdx.z;
    const int cl = tid & 63, q = tid >> 6;

    for (int r = q; r < 67; r += 4) {
        const int t = t0 - 3 + r;
        float v = 0.f;
        if (t >= 0) v = xz[((size_t)b * SEQ + t) * (2 * DI) + d0 + cl];
        tin[r][cl] = v;
    }
    __syncthreads();

    const float4 w = ((const float4*)cw)[d0 + cl];
    const float bb = cb[d0 + cl];
#pragma unroll
    for (int i = 0; i < 16; i++) {
        const int t = q * 16 + i;
        float a = bb;
        a = fmaf(tin[t + 0][cl], w.x, a);
        a = fmaf(tin[t + 1][cl], w.y, a);
        a = fmaf(tin[t + 2][cl], w.z, a);
        a = fmaf(tin[t + 3][cl], w.w, a);
        ttr[cl][t] = silu_fast(a);
    }
    __syncthreads();
#pragma unroll
    for (int i = 0; i < 16; i++) {
        const int d = q * 16 + i;
        uT[((size_t)b * DI + d0 + d) * SEQ + t0 + cl] = ttr[d][cl];
    }
}

// Tiled transpose: in[row=b*SEQ+t, coloff+c] (ld ldin) -> out[(b*ncols+c)*SEQ + t]
__global__ __launch_bounds__(256) void trans_r2t(
    const float* __restrict__ in, int ldin, int coloff,
    float* __restrict__ out, int ncols)
{
    __shared__ float tile[64][65];
    const int tid = threadIdx.x;
    const int c0 = blockIdx.x * 64, t0 = blockIdx.y * 64, b = blockIdx.z;
    const int cl = tid & 63, q = tid >> 6;
#pragma unroll
    for (int i = 0; i < 16; i++) {
        const int r = q * 16 + i;
        tile[r][cl] = in[((size_t)b * SEQ + t0 + r) * ldin + coloff + c0 + cl];
    }
    __syncthreads();
#pragma unroll
    for (int i = 0; i < 16; i++) {
        const int cc = q * 16 + i;
        out[((size_t)b * ncols + c0 + cc) * SEQ + t0 + cl] = tile[cl][cc];
    }
}

// B/C transpose into lane-interleaved layout:
//   bc4[(b*(SEQ/4) + t/4)*128 + ch] = float4{ x[t..t+3][ch] }
__global__ __launch_bounds__(256) void trans_bc_i4(
    const float* __restrict__ in, float4* __restrict__ bc4)
{
    __shared__ float tile[64][65];
    const int tid = threadIdx.x;
    const int c0 = blockIdx.x * 64, t0 = blockIdx.y * 64, b = blockIdx.z;
    const int cl = tid & 63, q = tid >> 6;
#pragma unroll
    for (int i = 0; i < 16; i++) {
        const int r = q * 16 + i;
        tile[r][cl] = in[((size_t)b * SEQ + t0 + r) * XDC + DTR + c0 + cl];
    }
    __syncthreads();
#pragma unroll
    for (int i = 0; i < 4; i++) {
        const int j = q * 4 + i;
        const float4 v = make_float4(tile[4 * j + 0][cl], tile[4 * j + 1][cl],
                                     tile[4 * j + 2][cl], tile[4 * j + 3][cl]);
        bc4[((size_t)b * (SEQ / 4) + (t0 / 4 + j)) * 128 + c0 + cl] = v;
    }
}

// ---------------- Chunked selective scan ----------------

__global__ __launch_bounds__(256, 4) void scan_phase1(
    const float* __restrict__ dtT, const float* __restrict__ uT,
    const float4* __restrict__ bc4, const float* __restrict__ A_log,
    float* __restrict__ hend, float* __restrict__ prodA)
{
    const int wid  = __builtin_amdgcn_readfirstlane(
                        (int)((blockIdx.x * 256 + threadIdx.x) >> 6));
    const int lane = threadIdx.x & 63;
    const int c  = wid & (NC - 1);
    const int bd = wid >> 3;
    const int b  = bd / DI;
    const int d  = bd - b * DI;

    const float An = -expf(A_log[d * DS + lane]) * LOG2E;
    const float* dtp = dtT + (size_t)bd * SEQ + c * TCH;
    const float* up  = uT  + (size_t)bd * SEQ + c * TCH;
    const float4* Bp = bc4 + ((size_t)b * (SEQ / 4) + c * (TCH / 4)) * 128 + lane;

    float4 Bc[4], Bn[4];
#pragma unroll
    for (int g = 0; g < 4; g++) Bc[g] = Bp[(size_t)g * 128];

    float h = 0.f, sdt = 0.f;
    for (int tb = 0; tb < TCH; tb += 16) {
        if (tb + 16 < TCH) {
#pragma unroll
            for (int g = 0; g < 4; g++)
                Bn[g] = Bp[(size_t)(tb / 4 + 4 + g) * 128];
        }
#pragma unroll
        for (int g = 0; g < 4; g++) {
            const float4 dt4 = *(const float4*)(dtp + tb + 4 * g);
            const float4 u4  = *(const float4*)(up  + tb + 4 * g);
            h = fmaf(exp2f(dt4.x * An), h, (dt4.x * u4.x) * Bc[g].x); sdt += dt4.x;
            h = fmaf(exp2f(dt4.y * An), h, (dt4.y * u4.y) * Bc[g].y); sdt += dt4.y;
            h = fmaf(exp2f(dt4.z * An), h, (dt4.z * u4.z) * Bc[g].z); sdt += dt4.z;
            h = fmaf(exp2f(dt4.w * An), h, (dt4.w * u4.w) * Bc[g].w); sdt += dt4.w;
        }
#pragma unroll
        for (int g = 0; g < 4; g++) Bc[g] = Bn[g];
    }
    hend [(size_t)wid * DS + lane] = h;
    prodA[(size_t)wid * DS + lane] = exp2f(An * sdt);
}

__global__ __launch_bounds__(256) void scan_phase2(
    float* __restrict__ hend, float* __restrict__ prodA)
{
    const int bd   = (blockIdx.x * 256 + threadIdx.x) >> 6;
    const int lane = threadIdx.x & 63;
    float h = 0.f;
#pragma unroll
    for (int c = 0; c < NC; c++) {
        const size_t off = ((size_t)bd * NC + c) * DS + lane;
        const float pA = prodA[off];
        const float he = hend[off];
        prodA[off] = h;
        h = fmaf(pA, h, he);
    }
}

__global__ __launch_bounds__(256, 4) void scan_phase3(
    float* dtsT,                                   // in: dtT, out: sT (aliased!)
    const float* __restrict__ uT, const float4* __restrict__ bc4,
    const float* __restrict__ A_log, const float* __restrict__ hin)
{
    __shared__ float red[4][16 * 65];
    const int wid  = __builtin_amdgcn_readfirstlane(
                        (int)((blockIdx.x * 256 + threadIdx.x) >> 6));
    const int lane = threadIdx.x & 63;
    const int c  = wid & (NC - 1);
    const int bd = wid >> 3;
    const int b  = bd / DI;
    const int d  = bd - b * DI;

    const float An = -expf(A_log[d * DS + lane]) * LOG2E;
    float* dtp = dtsT + (size_t)bd * SEQ + c * TCH;
    const float* up  = uT  + (size_t)bd * SEQ + c * TCH;
    const float4* Bp = bc4 + ((size_t)b * (SEQ / 4) + c * (TCH / 4)) * 128 + lane;
    const float4* Cp = Bp + 64;
    float* slab = &red[threadIdx.x >> 6][0];
    const int tt = lane & 15, seg = lane >> 4;

    float4 Bc[4], Cc[4], Bn[4], Cn[4];
#pragma unroll
    for (int g = 0; g < 4; g++) {
        Bc[g] = Bp[(size_t)g * 128];
        Cc[g] = Cp[(size_t)g * 128];
    }

    float h = hin[(size_t)wid * DS + lane];
    for (int tb = 0; tb < TCH; tb += 16) {
        if (tb + 16 < TCH) {
#pragma unroll
            for (int g = 0; g < 4; g++) {
                Bn[g] = Bp[(size_t)(tb / 4 + 4 + g) * 128];
                Cn[g] = Cp[(size_t)(tb / 4 + 4 + g) * 128];
            }
        }
        float p[16];
#pragma unroll
        for (int g = 0; g < 4; g++) {
            const float4 dt4 = *(const float4*)(dtp + tb + 4 * g);
            const float4 u4  = *(const float4*)(up  + tb + 4 * g);
            h = fmaf(exp2f(dt4.x * An), h, (dt4.x * u4.x) * Bc[g].x); p[4*g+0] = h * Cc[g].x;
            h = fmaf(exp2f(dt4.y * An), h, (dt4.y * u4.y) * Bc[g].y); p[4*g+1] = h * Cc[g].y;
            h = fmaf(exp2f(dt4.z * An), h, (dt4.z * u4.z) * Bc[g].z); p[4*g+2] = h * Cc[g].z;
            h = fmaf(exp2f(dt4.w * An), h, (dt4.w * u4.w) * Bc[g].w); p[4*g+3] = h * Cc[g].w;
        }
#pragma unroll
        for (int i = 0; i < 16; i++) slab[i * 65 + lane] = p[i];
        float s = 0.f;
#pragma unroll
        for (int j = 0; j < 16; j++) s += slab[tt * 65 + seg * 16 + j];
        s += __shfl_xor(s, 16, 64);
        s += __shfl_xor(s, 32, 64);
        if (lane < 16) dtp[tb + tt] = s;
#pragma unroll
        for (int g = 0; g < 4; g++) { Bc[g] = Bn[g]; Cc[g] = Cn[g]; }
    }
}

// Gate + transpose back: y[t][d] = (s + D*u) * silu(z) -> xz[:, 0:DI] row-major.
__global__ __launch_bounds__(256) void gate_t2r(
    const float* __restrict__ sT, const float* __restrict__ uT,
    const float* __restrict__ Dskip, float* __restrict__ xz)
{
    __shared__ float ts[64][65];
    __shared__ float tu[64][65];
    const int tid = threadIdx.x;
    const int d0 = blockIdx.x * 64, t0 = blockIdx.y * 64, b = blockIdx.z;
    const int cl = tid & 63, q = tid >> 6;
#pragma unroll
    for (int i = 0; i < 16; i++) {
        const int d = q * 16 + i;
        const size_t off = ((size_t)b * DI + d0 + d) * SEQ + t0 + cl;
        ts[cl][d] = sT[off];
        tu[cl][d] = uT[off];
    }
    __syncthreads();
    const float Dd = Dskip[d0 + cl];
#pragma unroll
    for (int i = 0; i < 16; i++) {
        const int t = q * 16 + i;
        const size_t row = (size_t)b * SEQ + t0 + t;
        const float z = xz[row * (2 * DI) + DI + d0 + cl];
        const float y = (ts[t][cl] + Dd * tu[t][cl]) * silu_fast(z);
        xz[row * (2 * DI) + d0 + cl] = y;
    }
}

extern "C" void kernel_launch(void* const* d_in, const int* in_sizes, int n_in,
                              void* d_out, int out_size, void* d_ws, size_t ws_size,
                              hipStream_t stream) {
    (void)in_sizes; (void)n_in; (void)out_size; (void)ws_size;
    const float* x    = (const float*)d_in[0];
    const float* Wi   = (const float*)d_in[1];
    const float* cw   = (const float*)d_in[2];
    const float* cb   = (const float*)d_in[3];
    const float* Wx   = (const float*)d_in[4];
    const float* Wdt  = (const float*)d_in[5];
    const float* bdt  = (const float*)d_in[6];
    const float* Alog = (const float*)d_in[7];
    const float* Dsk  = (const float*)d_in[8];
    const float* Wo   = (const float*)d_in[9];
    float* out = (float*)d_out;

    // Workspace (fp32), ~236 MB:
    float* xz    = (float*)d_ws;                          // [MROWS, 3072]
    float* uT    = xz    + (size_t)MROWS * (2 * DI);      // [B*DI, SEQ]  (also bf16-plane arena)
    float* dtT   = uT    + (size_t)MROWS * DI;            // [B*DI, SEQ]; sT after phase3
    float* xdbl  = dtT   + (size_t)MROWS * DI;            // [MROWS, 176]
    float* bcT   = xdbl  + (size_t)MROWS * XDC;           // [B][SEQ/4][128][4] interleaved
    float* xnext = bcT   + (size_t)BATCH * 128 * SEQ;     // [MROWS, 768]
    float* hend  = xnext;                                 // [B*DI*NC, DS] (aliases xnext)
    float* prodA = xnext + (size_t)BATCH * DI * NC * DS;  // [B*DI*NC, DS]

    // bf16 plane arena 1 (aliases uT; dead before conv writes uT):
    ushort_t* sh  = (ushort_t*)uT;                        // [MROWS, DM]
    ushort_t* sl  = sh  + (size_t)MROWS * DM;
    ushort_t* wih = sl  + (size_t)MROWS * DM;             // [2*DI, DM]
    ushort_t* wil = wih + (size_t)2 * DI * DM;
    // bf16 plane arena 2 (aliases uT+dtT; dead after gate_t2r):
    ushort_t* yh  = (ushort_t*)uT;                        // [MROWS, DI]
    ushort_t* yl  = yh  + (size_t)MROWS * DI;
    ushort_t* woh = yl  + (size_t)MROWS * DI;             // [DM, DI]
    ushort_t* wol = woh + (size_t)DM * DI;

    const float* src = x;
    for (int i = 0; i < DEPTH; i++) {
        const float* Wi_l   = Wi   + (size_t)i * 2 * DI * DM;
        const float* cw_l   = cw   + (size_t)i * DI * DC;
        const float* cb_l   = cb   + (size_t)i * DI;
        const float* Wx_l   = Wx   + (size_t)i * XDC * DI;
        const float* Wdt_l  = Wdt  + (size_t)i * DI * DTR;
        const float* bdt_l  = bdt  + (size_t)i * DI;
        const float* Alog_l = Alog + (size_t)i * DI * DS;
        const float* Dsk_l  = Dsk  + (size_t)i * DI;
        const float* Wo_l   = Wo   + (size_t)i * DM * DI;
        float* dst = (i == DEPTH - 1) ? out : xnext;

        // 1. split src and Wi to bf16 hi/lo planes
        split_bf16<<<(size_t)MROWS * DM / 1024, 256, 0, stream>>>(src, sh, sl);
        split_bf16<<<(size_t)2 * DI * DM / 1024, 256, 0, stream>>>(Wi_l, wih, wil);
        // 2. xz = src @ Wi^T  (bf16x2 MFMA)        [8192, 3072]
        gemm_mfma<<<dim3(2 * DI / 128, MROWS / 128), 256, 0, stream>>>(
            sh, sl, wih, wil, xz, 2 * DI, DM);
        // 3. uT = silu(conv(xz[:, :DI])) transposed [b][d][t] (overwrites planes)
        conv_silu_T<<<dim3(DI / 64, SEQ / 64, BATCH), 256, 0, stream>>>(
            xz, cw_l, cb_l, uT);
        // 4. xdbl = u @ Wx^T via k-major uT        [8192, 176]
        gemm_tn<<<dim3((XDC + 127) / 128, MROWS / 128), 256, 0, stream>>>(
            uT, Wx_l, xdbl, XDC, XDC, DI);
        // 5. B/C -> lane-interleaved bc4 layout
        trans_bc_i4<<<dim3(2, SEQ / 64, BATCH), 256, 0, stream>>>(
            xdbl, (float4*)bcT);
        // 6. dt = softplus(xdbl[:, :48] @ Wdt^T + bdt) -> xz[:, 0:DI]
        gemm_dt<<<dim3(DI / 128, MROWS / 128), 256, 0, stream>>>(
            xdbl, XDC, Wdt_l, bdt_l, xz, 2 * DI, DI, DTR);
        // 7. dt transpose -> dtT [b][d][t]
        trans_r2t<<<dim3(DI / 64, SEQ / 64, BATCH), 256, 0, stream>>>(
            xz, 2 * DI, 0, dtT, DI);
        // 8-10. chunked scan; phase3 writes raw s in place over dtT
        scan_phase1<<<(BATCH * DI * NC) / 4, 256, 0, stream>>>(
            dtT, uT, (const float4*)bcT, Alog_l, hend, prodA);
        scan_phase2<<<(BATCH * DI) / 4, 256, 0, stream>>>(hend, prodA);
        scan_phase3<<<(BATCH * DI * NC) / 4, 256, 0, stream>>>(
            dtT, uT, (const float4*)bcT, Alog_l, prodA);
        // 11. gate + transpose: y -> xz[:, :DI] row-major
        gate_t2r<<<dim3(DI / 64, SEQ / 64, BATCH), 256, 0, stream>>>(
            dtT, uT, Dsk_l, xz);
        // 12. split y and Wo to bf16 hi/lo planes (uT/dtT arena, both dead)
        split_bf16_y<<<(size_t)MROWS * DI / 1024, 256, 0, stream>>>(xz, yh, yl);
        split_bf16<<<(size_t)DM * DI / 1024, 256, 0, stream>>>(Wo_l, woh, wol);
        // 13. dst = y @ Wo^T  (bf16x2 MFMA)        [8192, 768]
        gemm_mfma<<<dim3(DM / 128, MROWS / 128), 256, 0, stream>>>(
            yh, yl, woh, wol, dst, DM, DI);

        src = dst;
    }
}